// Round 1
// baseline (450.657 us; speedup 1.0000x reference)
//
#include <hip/hip_runtime.h>
#include <hip/hip_bf16.h>

#define NE 40000
#define FD 768
#define ED 256
#define NB 32
#define OUTC (NE + 1)

// ---------------------------------------------------------------------------
// K1: query_sum (32x256) into ws, plus score[:,0] (vs unity row 0 = other_emb[0])
// one block per batch element; thread t = embedding dim d
// ---------------------------------------------------------------------------
__global__ __launch_bounds__(256) void qsum_score0_kernel(
    const float* __restrict__ ent_pkl,
    const float* __restrict__ other_emb,
    const float* __restrict__ proj_W,
    const int* __restrict__ ids,
    const int* __restrict__ mpos,
    float* __restrict__ qs,
    float* __restrict__ out)
{
    __shared__ float row[FD];
    __shared__ float red[4];
    __shared__ float bc;

    const int b = blockIdx.x;
    const int t = threadIdx.x;
    const int mp = mpos[0];  // works for int32 or little-endian int64 (value 0..2)

    // Detect int64 vs int32 storage of batch_input_ids: under int64 the
    // high words (odd int32 indices) of the first values are all zero.
    const bool wide = (ids[1] == 0 && ids[3] == 0 && ids[5] == 0);

    float acc = 0.f;
    for (int s = 0; s < 3; ++s) {
        if (s == mp) continue;  // query_input = ids[:, all cols != mp]
        const int flat = b * 3 + s;
        const int idx = wide ? ids[flat * 2] : ids[flat];

        float v;
        __syncthreads();  // protect row/red/bc reuse across iterations
        if (idx >= 1 && idx <= NE) {
            const int e = idx - 1;
            for (int k = t; k < FD; k += 256) row[k] = ent_pkl[(size_t)e * FD + k];
            __syncthreads();
            const float4* wr = (const float4*)(proj_W + (size_t)t * FD);
            const float4* rr = (const float4*)row;
            float vv = 0.f;
#pragma unroll 4
            for (int k4 = 0; k4 < FD / 4; ++k4) {
                float4 w = wr[k4];
                float4 r = rr[k4];
                vv += w.x * r.x;
                vv += w.y * r.y;
                vv += w.z * r.z;
                vv += w.w * r.w;
            }
            v = vv;
        } else if (idx == 0) {
            v = other_emb[t];
        } else {  // idx > NE: other_emb[idx - NE]
            v = other_emb[(size_t)(idx - NE) * ED + t];
        }

        // block reduction of sum(v*v)
        float ss = v * v;
#pragma unroll
        for (int o = 32; o > 0; o >>= 1) ss += __shfl_down(ss, o, 64);
        if ((t & 63) == 0) red[t >> 6] = ss;
        __syncthreads();
        if (t == 0) bc = fmaxf(sqrtf(red[0] + red[1] + red[2] + red[3]), 1e-12f);
        __syncthreads();
        acc += v / bc;
    }

    qs[b * ED + t] = acc;

    // score[b][0] = -sum_d |qs[b][d] - other_emb[0][d]|
    float d0 = fabsf(acc - other_emb[t]);
#pragma unroll
    for (int o = 32; o > 0; o >>= 1) d0 += __shfl_down(d0, o, 64);
    __syncthreads();
    if ((t & 63) == 0) red[t >> 6] = d0;
    __syncthreads();
    if (t == 0) out[(size_t)b * OUTC] = -(red[0] + red[1] + red[2] + red[3]);
}

// ---------------------------------------------------------------------------
// K2: fused fp32 GEMM (64x256 tile of ent_proj) + L1-distance scoring.
// 625 blocks x 256 threads. BK=32. Micro-tile 2x2x4x4 (64 acc / thread):
//   row = ri*32 + ry*4 + i, col = ci*128 + cx*4 + j   (ry=t>>5, cx=t&31)
// Score phase reuses Bs (32 KB) to stage 32 ent_proj rows at a time.
// ---------------------------------------------------------------------------
__global__ __launch_bounds__(256) void gemm_score_kernel(
    const float* __restrict__ ent_pkl,
    const float* __restrict__ proj_W,
    const float* __restrict__ qs,
    float* __restrict__ out)
{
    __shared__ float As[32][64];    // [k][row]  8 KB
    __shared__ float Bs[32][256];   // [k][col] 32 KB (reused as S[32][256] for scoring)

    const int t = threadIdx.x;
    const int e0 = blockIdx.x * 64;
    const int ry = t >> 5;   // 0..7
    const int cx = t & 31;   // 0..31
    const int srow = t >> 2; // 0..63 (staging row)
    const int skq = t & 3;   // 0..3  (staging k-quad: k = skq*8 + 0..7)

    float acc[2][2][4][4];
#pragma unroll
    for (int a = 0; a < 2; ++a)
#pragma unroll
        for (int c = 0; c < 2; ++c)
#pragma unroll
            for (int i = 0; i < 4; ++i)
#pragma unroll
                for (int j = 0; j < 4; ++j) acc[a][c][i][j] = 0.f;

    for (int k0 = 0; k0 < FD; k0 += 32) {
        __syncthreads();
        // stage A tile: ent_pkl rows e0..e0+63, k = k0..k0+31, transposed to [k][row]
        {
            const float* src = ent_pkl + (size_t)(e0 + srow) * FD + k0 + skq * 8;
            float4 a0 = ((const float4*)src)[0];
            float4 a1 = ((const float4*)src)[1];
            float av8[8] = {a0.x, a0.y, a0.z, a0.w, a1.x, a1.y, a1.z, a1.w};
#pragma unroll
            for (int j = 0; j < 8; ++j) As[skq * 8 + j][srow] = av8[j];
        }
        // stage B tile: proj_W rows (=output dims) 0..255, k chunk, transposed to [k][d]
#pragma unroll
        for (int p = 0; p < 4; ++p) {
            const int d = p * 64 + srow;
            const float* src = proj_W + (size_t)d * FD + k0 + skq * 8;
            float4 b0 = ((const float4*)src)[0];
            float4 b1 = ((const float4*)src)[1];
            float bv8[8] = {b0.x, b0.y, b0.z, b0.w, b1.x, b1.y, b1.z, b1.w};
#pragma unroll
            for (int j = 0; j < 8; ++j) Bs[skq * 8 + j][d] = bv8[j];
        }
        __syncthreads();

#pragma unroll 8
        for (int k = 0; k < 32; ++k) {
            float4 a0 = *(const float4*)&As[k][ry * 4];
            float4 a1 = *(const float4*)&As[k][32 + ry * 4];
            float4 b0 = *(const float4*)&Bs[k][cx * 4];
            float4 b1 = *(const float4*)&Bs[k][128 + cx * 4];
            float av[2][4] = {{a0.x, a0.y, a0.z, a0.w}, {a1.x, a1.y, a1.z, a1.w}};
            float bv[2][4] = {{b0.x, b0.y, b0.z, b0.w}, {b1.x, b1.y, b1.z, b1.w}};
#pragma unroll
            for (int ri = 0; ri < 2; ++ri)
#pragma unroll
                for (int i = 0; i < 4; ++i)
#pragma unroll
                    for (int ci = 0; ci < 2; ++ci)
#pragma unroll
                        for (int j = 0; j < 4; ++j)
                            acc[ri][ci][i][j] += av[ri][i] * bv[ci][j];
        }
    }

    // ---- score phase: two batches of 32 entity rows staged through Bs ----
    const int b = t & 31;    // batch element
    const int eg = t >> 5;   // entity group: entities eg*4 .. eg*4+3 (local)
    const float* qrow = qs + b * ED;

#pragma unroll
    for (int ph = 0; ph < 2; ++ph) {
        __syncthreads();
        // write rows ph*32 .. ph*32+31 of the tile into Bs as S[erow][d]
#pragma unroll
        for (int i = 0; i < 4; ++i) {
#pragma unroll
            for (int ci = 0; ci < 2; ++ci) {
                float4 v;
                v.x = acc[ph][ci][i][0];
                v.y = acc[ph][ci][i][1];
                v.z = acc[ph][ci][i][2];
                v.w = acc[ph][ci][i][3];
                *(float4*)&Bs[ry * 4 + i][ci * 128 + cx * 4] = v;
            }
        }
        __syncthreads();

        float sc0 = 0.f, sc1 = 0.f, sc2 = 0.f, sc3 = 0.f;
#pragma unroll 4
        for (int d = 0; d < ED; d += 4) {
            float4 q = *(const float4*)(qrow + d);
            float4 x0 = *(const float4*)&Bs[eg * 4 + 0][d];
            float4 x1 = *(const float4*)&Bs[eg * 4 + 1][d];
            float4 x2 = *(const float4*)&Bs[eg * 4 + 2][d];
            float4 x3 = *(const float4*)&Bs[eg * 4 + 3][d];
            sc0 += fabsf(q.x - x0.x) + fabsf(q.y - x0.y) + fabsf(q.z - x0.z) + fabsf(q.w - x0.w);
            sc1 += fabsf(q.x - x1.x) + fabsf(q.y - x1.y) + fabsf(q.z - x1.z) + fabsf(q.w - x1.w);
            sc2 += fabsf(q.x - x2.x) + fabsf(q.y - x2.y) + fabsf(q.z - x2.z) + fabsf(q.w - x2.w);
            sc3 += fabsf(q.x - x3.x) + fabsf(q.y - x3.y) + fabsf(q.z - x3.z) + fabsf(q.w - x3.w);
        }
        // out column index = 1 + global entity index
        float* op = out + (size_t)b * OUTC + 1 + e0 + ph * 32 + eg * 4;
        op[0] = -sc0;
        op[1] = -sc1;
        op[2] = -sc2;
        op[3] = -sc3;
    }
}

extern "C" void kernel_launch(void* const* d_in, const int* in_sizes, int n_in,
                              void* d_out, int out_size, void* d_ws, size_t ws_size,
                              hipStream_t stream) {
    const float* ent_pkl = (const float*)d_in[0];
    const float* other_emb = (const float*)d_in[1];
    const float* proj_W = (const float*)d_in[2];
    const int* ids = (const int*)d_in[3];
    const int* mpos = (const int*)d_in[4];
    float* out = (float*)d_out;
    float* qs = (float*)d_ws;  // 32x256 fp32 = 32 KB

    qsum_score0_kernel<<<NB, 256, 0, stream>>>(ent_pkl, other_emb, proj_W, ids, mpos, qs, out);
    gemm_score_kernel<<<NE / 64, 256, 0, stream>>>(ent_pkl, proj_W, qs, out);
}

// Round 2
// 309.310 us; speedup vs baseline: 1.4570x; 1.4570x over previous
//
#include <hip/hip_runtime.h>
#include <hip/hip_bf16.h>
#include <stdint.h>

#define NE 40000
#define FD 768
#define ED 256
#define NB 32
#define OUTC (NE + 1)

typedef __bf16 bf16x8 __attribute__((ext_vector_type(8)));
typedef float f32x4 __attribute__((ext_vector_type(4)));
typedef unsigned short ushortx8 __attribute__((ext_vector_type(8)));

// ws layout: [0,32K) qs fp32[32][256] ; [32K,96K) n01 fp32[64][256] ;
//            [96K,480K) W_bf16[256][768]
#define WS_QS 0
#define WS_N01 (32 * 1024)
#define WS_WB (96 * 1024)

__device__ __forceinline__ unsigned short f2bf(float x) {
    union { float f; unsigned u; } v; v.f = x;
    unsigned r = v.u + 0x7fffu + ((v.u >> 16) & 1u);  // RNE
    return (unsigned short)(r >> 16);
}

__device__ __forceinline__ void glds16(const void* g, void* l) {
    __builtin_amdgcn_global_load_lds(
        (const __attribute__((address_space(1))) void*)g,
        (__attribute__((address_space(3))) void*)l, 16, 0, 0);
}

// ---------------------------------------------------------------------------
// K0: proj_W fp32 -> bf16 (256x768). 192 blocks x 256 thr, 1 float4/thread.
// ---------------------------------------------------------------------------
__global__ __launch_bounds__(256) void wcvt_kernel(
    const float* __restrict__ W, unsigned short* __restrict__ Wb)
{
    int i = (blockIdx.x * 256 + threadIdx.x) * 4;
    float4 v = *(const float4*)(W + i);
    ushort4 o;
    o.x = f2bf(v.x); o.y = f2bf(v.y); o.z = f2bf(v.z); o.w = f2bf(v.w);
    *(ushort4*)(Wb + i) = o;
}

// ---------------------------------------------------------------------------
// K1a: one block per (batch, slot): normalized embedding row -> n01.
// ---------------------------------------------------------------------------
__global__ __launch_bounds__(256) void qnorm_kernel(
    const float* __restrict__ ent_pkl, const float* __restrict__ other_emb,
    const float* __restrict__ W, const int* __restrict__ ids,
    const int* __restrict__ mpos, float* __restrict__ n01)
{
    __shared__ float row[FD];
    __shared__ float red[4];
    __shared__ float nrm;

    const int bid = blockIdx.x;
    const int t = threadIdx.x;
    const int b = bid >> 1, s = bid & 1;
    const int mp = mpos[0];
    const int col = (s < mp) ? s : s + 1;  // cols of {0,1,2} minus mp
    const bool wide = (ids[1] == 0 && ids[3] == 0 && ids[5] == 0);  // int64?
    const int flat = b * 3 + col;
    const int idx = wide ? ids[flat * 2] : ids[flat];

    float v;
    if (idx >= 1 && idx <= NE) {  // entity: project
        const float* src = ent_pkl + (size_t)(idx - 1) * FD;
        for (int k = t; k < FD; k += 256) row[k] = src[k];
        __syncthreads();
        const float4* wr4 = (const float4*)(W + (size_t)t * FD);
        const float4* rr4 = (const float4*)row;
        float a0 = 0.f, a1 = 0.f, a2 = 0.f, a3 = 0.f;
#pragma unroll 2
        for (int k4 = 0; k4 < FD / 4; k4 += 4) {
            float4 w0 = wr4[k4 + 0], r0 = rr4[k4 + 0];
            float4 w1 = wr4[k4 + 1], r1 = rr4[k4 + 1];
            float4 w2 = wr4[k4 + 2], r2 = rr4[k4 + 2];
            float4 w3 = wr4[k4 + 3], r3 = rr4[k4 + 3];
            a0 += w0.x * r0.x + w0.y * r0.y + w0.z * r0.z + w0.w * r0.w;
            a1 += w1.x * r1.x + w1.y * r1.y + w1.z * r1.z + w1.w * r1.w;
            a2 += w2.x * r2.x + w2.y * r2.y + w2.z * r2.z + w2.w * r2.w;
            a3 += w3.x * r3.x + w3.y * r3.y + w3.z * r3.z + w3.w * r3.w;
        }
        v = (a0 + a1) + (a2 + a3);
    } else if (idx == 0) {
        v = other_emb[t];
    } else {  // idx > NE
        v = other_emb[(size_t)(idx - NE) * ED + t];
    }

    float ss = v * v;
#pragma unroll
    for (int o = 32; o > 0; o >>= 1) ss += __shfl_down(ss, o, 64);
    if ((t & 63) == 0) red[t >> 6] = ss;
    __syncthreads();
    if (t == 0) nrm = fmaxf(sqrtf(red[0] + red[1] + red[2] + red[3]), 1e-12f);
    __syncthreads();
    n01[bid * ED + t] = v / nrm;
}

// ---------------------------------------------------------------------------
// K1b: qs = n0 + n1 per batch; score column 0 (vs other_emb row 0).
// ---------------------------------------------------------------------------
__global__ __launch_bounds__(256) void qsum_kernel(
    const float* __restrict__ n01, const float* __restrict__ other_emb,
    float* __restrict__ qs, float* __restrict__ out)
{
    __shared__ float red[4];
    const int b = blockIdx.x, t = threadIdx.x;
    const float v = n01[(b * 2) * ED + t] + n01[(b * 2 + 1) * ED + t];
    qs[b * ED + t] = v;
    float d = fabsf(v - other_emb[t]);
#pragma unroll
    for (int o = 32; o > 0; o >>= 1) d += __shfl_down(d, o, 64);
    if ((t & 63) == 0) red[t >> 6] = d;
    __syncthreads();
    if (t == 0) out[(size_t)b * OUTC] = -(red[0] + red[1] + red[2] + red[3]);
}

// ---------------------------------------------------------------------------
// K2: bf16 MFMA GEMM (64 rows x 256 dims per block, K=768) + fused scoring.
// 625 blocks x 256 thr (4 waves as 2x2: each wave 32 rows x 128 cols).
// B staged via global_load_lds (bf16 ws), A converted fp32->bf16 in-flight.
// Scoring reuses LDS as S[32][260] in two 32-row phases.
// ---------------------------------------------------------------------------
__global__ __launch_bounds__(256) void gemm_score_kernel(
    const float* __restrict__ ent_pkl, const unsigned short* __restrict__ Wb,
    const float* __restrict__ qs, float* __restrict__ out)
{
    __shared__ __align__(16) unsigned char smem[33280];
    unsigned short* As = (unsigned short*)smem;           // [64][32] bf16
    unsigned short* Bs = (unsigned short*)(smem + 4096);  // [256][32] bf16
    float* S = (float*)smem;                              // [32][260] fp32

    const int t = threadIdx.x;
    const int l = t & 63;
    const int w = t >> 6;     // wave 0..3
    const int wr = w >> 1;    // row strip (32 rows)
    const int wc = w & 1;     // col strip (128 cols)
    const int ln15 = l & 15;
    const int lq = l >> 4;    // 0..3
    const int e0 = blockIdx.x * 64;

    f32x4 acc[2][8];
#pragma unroll
    for (int s = 0; s < 2; ++s)
#pragma unroll
        for (int c = 0; c < 8; ++c) acc[s][c] = (f32x4){0.f, 0.f, 0.f, 0.f};

    // A staging coords: thread t stages row t>>2, k-octet (t&3)*8
    const int arow = t >> 2;
    const int akq = (t & 3) * 8;
    const float* aptr = ent_pkl + (size_t)(e0 + arow) * FD + akq;

    for (int k0 = 0; k0 < FD; k0 += 32) {
        // A fp32 -> regs (issued before barrier: overlaps prior compute)
        float4 a0 = *(const float4*)(aptr + k0);
        float4 a1 = *(const float4*)(aptr + k0 + 4);
        __syncthreads();  // prior chunk's LDS reads done before overwrite
        // B: 4 glds rounds/wave; lane i -> dim base+(i>>2), k (i&3)*8 (16B)
#pragma unroll
        for (int r = 0; r < 4; ++r) {
            const int dimbase = r * 64 + w * 16;
            const unsigned short* g =
                Wb + (size_t)(dimbase + (l >> 2)) * FD + k0 + (l & 3) * 8;
            glds16(g, Bs + dimbase * 32);
        }
        // A cvt + LDS write
        ushortx8 av;
        av[0] = f2bf(a0.x); av[1] = f2bf(a0.y); av[2] = f2bf(a0.z); av[3] = f2bf(a0.w);
        av[4] = f2bf(a1.x); av[5] = f2bf(a1.y); av[6] = f2bf(a1.z); av[7] = f2bf(a1.w);
        *(ushortx8*)(As + arow * 32 + akq) = av;
        __syncthreads();  // drains vmcnt (glds) + lgkm (ds_write)

        // compute: 2 a-frags, 8 b-frags (each reused for both row strips)
        bf16x8 af0 = *(const bf16x8*)(As + (wr * 32 + ln15) * 32 + lq * 8);
        bf16x8 af1 = *(const bf16x8*)(As + (wr * 32 + 16 + ln15) * 32 + lq * 8);
#pragma unroll
        for (int c = 0; c < 8; ++c) {
            bf16x8 bf = *(const bf16x8*)(Bs + (wc * 128 + c * 16 + ln15) * 32 + lq * 8);
            acc[0][c] = __builtin_amdgcn_mfma_f32_16x16x32_bf16(af0, bf, acc[0][c], 0, 0, 0);
            acc[1][c] = __builtin_amdgcn_mfma_f32_16x16x32_bf16(af1, bf, acc[1][c], 0, 0, 0);
        }
    }

    // ---- scoring: 2 phases of 32 entity rows through S ----
    const int b0 = (t & 15) * 2;   // batches b0, b0+1
    const int el = (t >> 4) * 2;   // local entities el, el+1
    const float* q0 = qs + b0 * ED;
    const float* q1 = q0 + ED;

#pragma unroll
    for (int ph = 0; ph < 2; ++ph) {
        __syncthreads();  // prior phase reads / GEMM frag reads done
        if (wr == ph) {   // C/D layout: col=lane&15, row=lq*4+reg
#pragma unroll
            for (int s = 0; s < 2; ++s)
#pragma unroll
                for (int c = 0; c < 8; ++c)
#pragma unroll
                    for (int r = 0; r < 4; ++r)
                        S[(s * 16 + lq * 4 + r) * 260 + wc * 128 + c * 16 + ln15] =
                            acc[s][c][r];
        }
        __syncthreads();

        float s00 = 0.f, s01 = 0.f, s10 = 0.f, s11 = 0.f;
        const float* e0p = S + el * 260;
        const float* e1p = S + (el + 1) * 260;
#pragma unroll 4
        for (int d = 0; d < ED; d += 4) {
            float4 qa = *(const float4*)(q0 + d);
            float4 qb = *(const float4*)(q1 + d);
            float4 ea = *(const float4*)(e0p + d);
            float4 eb = *(const float4*)(e1p + d);
            s00 += fabsf(qa.x - ea.x) + fabsf(qa.y - ea.y) + fabsf(qa.z - ea.z) + fabsf(qa.w - ea.w);
            s01 += fabsf(qa.x - eb.x) + fabsf(qa.y - eb.y) + fabsf(qa.z - eb.z) + fabsf(qa.w - eb.w);
            s10 += fabsf(qb.x - ea.x) + fabsf(qb.y - ea.y) + fabsf(qb.z - ea.z) + fabsf(qb.w - ea.w);
            s11 += fabsf(qb.x - eb.x) + fabsf(qb.y - eb.y) + fabsf(qb.z - eb.z) + fabsf(qb.w - eb.w);
        }
        const int ec = 1 + e0 + ph * 32 + el;
        out[(size_t)b0 * OUTC + ec] = -s00;
        out[(size_t)b0 * OUTC + ec + 1] = -s01;
        out[(size_t)(b0 + 1) * OUTC + ec] = -s10;
        out[(size_t)(b0 + 1) * OUTC + ec + 1] = -s11;
    }
}

extern "C" void kernel_launch(void* const* d_in, const int* in_sizes, int n_in,
                              void* d_out, int out_size, void* d_ws, size_t ws_size,
                              hipStream_t stream) {
    const float* ent_pkl = (const float*)d_in[0];
    const float* other_emb = (const float*)d_in[1];
    const float* proj_W = (const float*)d_in[2];
    const int* ids = (const int*)d_in[3];
    const int* mpos = (const int*)d_in[4];
    float* out = (float*)d_out;

    float* qs = (float*)((char*)d_ws + WS_QS);
    float* n01 = (float*)((char*)d_ws + WS_N01);
    unsigned short* Wb = (unsigned short*)((char*)d_ws + WS_WB);

    wcvt_kernel<<<(ED * FD) / 1024, 256, 0, stream>>>(proj_W, Wb);
    qnorm_kernel<<<NB * 2, 256, 0, stream>>>(ent_pkl, other_emb, proj_W, ids, mpos, n01);
    qsum_kernel<<<NB, 256, 0, stream>>>(n01, other_emb, qs, out);
    gemm_score_kernel<<<NE / 64, 256, 0, stream>>>(ent_pkl, Wb, qs, out);
}